// Round 4
// baseline (381.091 us; speedup 1.0000x reference)
//
#include <hip/hip_runtime.h>
#include <hip/hip_bf16.h>

#define NCOL 10752   // 512*21
#define NROW 2048
#define NG 15
#define NTILES 23

typedef __bf16 bf16;
typedef __attribute__((ext_vector_type(8))) __bf16 bf16x8;
typedef __attribute__((ext_vector_type(4))) __bf16 bf16x4;
typedef __attribute__((ext_vector_type(4))) float f32x4;

__constant__ int c_gsize[NG]  = {64,128,256,96,160,224,192,288,320,112,80,48,32,16,32};
__constant__ int c_gstart[NG] = {0,64,192,448,544,704,928,1120,1408,1728,1840,1920,1968,2000,2016};
// tiles sorted by descending group size; grid.x = colb so adjacent blocks stream
// adjacent 512B col-segments of the same X k-rows (page coalescing + L3 reuse).
__constant__ int c_tgrp[NTILES] = {8,8,8,7,7,7,2,2,5,5,6,6,4,4,1,9,3,10,0,11,12,14,13};
__constant__ int c_trow[NTILES] = {0,128,256,0,128,256,0,128,0,128,0,128,0,128,0,0,0,0,0,0,0,0,0};

struct MatPtrs { const float* p[NG]; };

constexpr int BM = 128, BN = 128, BK = 32, BKp = 40;

// A-fragments come straight from global (M is 1.7MB total, L2-resident, re-read
// by all 84 col-blocks). Only X needs LDS (transpose k->contiguous for frags).
__global__ __launch_bounds__(256, 4)
void matapply_kernel(const float* __restrict__ x, MatPtrs mats, float* __restrict__ out)
{
    // double-buffered B only: 2 * 128*40 * 2B = 20 KB
    __shared__ bf16 sB[2][BN][BKp];   // [col][k], k-chunk XOR-swizzled by (col>>3)&3

    const int tid    = threadIdx.x;
    const int colb   = blockIdx.x * BN;
    const int tileid = blockIdx.y;

    const int grp  = c_tgrp[tileid];
    const int row0 = c_trow[tileid];
    const int g    = c_gsize[grp];
    const int s    = c_gstart[grp];
    const float* __restrict__ M = mats.p[grp];

    const int wave = tid >> 6;
    const int lane = tid & 63;
    const int wr   = (wave & 1) * 64;
    const int wc   = (wave >> 1) * 64;
    const int lm   = lane & 15;
    const int kq   = lane >> 4;
    const int kb   = kq * 8;

    // X staging: thread loads 4 k-rows (bK..bK+3) x 4 cols (bC..bC+3)
    const int bC = (tid & 31) * 4;
    const int bK = (tid >> 5) * 4;

    const int nIter = (g + BK - 1) / BK;

    f32x4 acc[4][4];
    #pragma unroll
    for (int i = 0; i < 4; i++)
        #pragma unroll
        for (int j = 0; j < 4; j++)
            acc[i][j] = (f32x4){0.f, 0.f, 0.f, 0.f};

    float4 xv[4];      // X prefetch regs
    float4 a4[4][2];   // A prefetch regs (4 frags x 8 fp32)

    // per-lane A addressing: row = row0+wr+i*16+lm, k-chunk = k0+kb
    int arow[4]; bool arok[4];
    #pragma unroll
    for (int i = 0; i < 4; i++) {
        arow[i] = row0 + wr + i * 16 + lm;
        arok[i] = arow[i] < g;
    }

    // ---- prologue: load iter 0 ----
    #pragma unroll
    for (int i = 0; i < 4; i++) {
        a4[i][0] = make_float4(0.f,0.f,0.f,0.f);
        a4[i][1] = make_float4(0.f,0.f,0.f,0.f);
        if (arok[i] && kb < g) {
            const float* p = M + (size_t)arow[i] * g + kb;
            a4[i][0] = *(const float4*)p;
            a4[i][1] = *(const float4*)(p + 4);
        }
    }
    #pragma unroll
    for (int j = 0; j < 4; j++)
        xv[j] = *(const float4*)(x + (size_t)(s + bK + j) * NCOL + colb + bC);

    // stage X iter 0 -> buf 0
    #pragma unroll
    for (int cc = 0; cc < 4; cc++) {
        int lc = bC + cc;
        bf16x4 w;
        #pragma unroll
        for (int j = 0; j < 4; j++)
            w[j] = (bf16)(((const float*)&xv[j])[cc]);
        *(bf16x4*)&sB[0][lc][bK ^ (((lc >> 3) & 3) << 3)] = w;
    }
    __syncthreads();

    for (int it = 0; it < nIter; ++it) {
        const int cur = it & 1;
        const bool more = (it + 1) < nIter;

        // convert this iter's A (loaded last iter) to bf16 frags
        bf16x8 af[4];
        #pragma unroll
        for (int i = 0; i < 4; i++) {
            #pragma unroll
            for (int e = 0; e < 4; e++) {
                af[i][e]     = (bf16)(((const float*)&a4[i][0])[e]);
                af[i][4 + e] = (bf16)(((const float*)&a4[i][1])[e]);
            }
        }

        // ---- issue next iter's global loads (in flight during compute) ----
        if (more) {
            const int k0 = (it + 1) * BK;
            #pragma unroll
            for (int i = 0; i < 4; i++) {
                a4[i][0] = make_float4(0.f,0.f,0.f,0.f);
                a4[i][1] = make_float4(0.f,0.f,0.f,0.f);
                if (arok[i] && (k0 + kb) < g) {
                    const float* p = M + (size_t)arow[i] * g + k0 + kb;
                    a4[i][0] = *(const float4*)p;
                    a4[i][1] = *(const float4*)(p + 4);
                }
            }
            #pragma unroll
            for (int j = 0; j < 4; j++)
                xv[j] = *(const float4*)(x + (size_t)(s + k0 + bK + j) * NCOL + colb + bC);
        }

        // ---- compute from sB[cur] ----
        bf16x8 bfr[4];
        #pragma unroll
        for (int j = 0; j < 4; j++) {
            int lc = wc + j * 16 + lm;
            bfr[j] = *(const bf16x8*)&sB[cur][lc][kb ^ (((lc >> 3) & 3) << 3)];
        }
        #pragma unroll
        for (int i = 0; i < 4; i++)
            #pragma unroll
            for (int j = 0; j < 4; j++)
                acc[i][j] = __builtin_amdgcn_mfma_f32_16x16x32_bf16(af[i], bfr[j], acc[i][j], 0, 0, 0);

        // ---- drain X loads, stage into buf[1-cur], one barrier ----
        if (more) {
            const int nxt = 1 - cur;
            #pragma unroll
            for (int cc = 0; cc < 4; cc++) {
                int lc = bC + cc;
                bf16x4 w;
                #pragma unroll
                for (int j = 0; j < 4; j++)
                    w[j] = (bf16)(((const float*)&xv[j])[cc]);
                *(bf16x4*)&sB[nxt][lc][bK ^ (((lc >> 3) & 3) << 3)] = w;
            }
            __syncthreads();
        }
    }

    // ---- epilogue: C/D layout col=lane&15, row=(lane>>4)*4+reg ----
    #pragma unroll
    for (int i = 0; i < 4; i++) {
        #pragma unroll
        for (int r = 0; r < 4; r++) {
            int row = row0 + wr + i * 16 + kq * 4 + r;
            if (row < g) {
                float* orow = out + (size_t)(s + row) * NCOL + colb + wc;
                #pragma unroll
                for (int j = 0; j < 4; j++)
                    orow[j * 16 + lm] = acc[i][j][r];
            }
        }
    }
}

extern "C" void kernel_launch(void* const* d_in, const int* in_sizes, int n_in,
                              void* d_out, int out_size, void* d_ws, size_t ws_size,
                              hipStream_t stream)
{
    const float* x = (const float*)d_in[0];
    MatPtrs mp;
    for (int i = 0; i < NG; i++) mp.p[i] = (const float*)d_in[1 + i];
    float* out = (float*)d_out;

    dim3 grid(NCOL / BN, NTILES);   // (84, 23): colb fastest
    dim3 block(256);
    matapply_kernel<<<grid, block, 0, stream>>>(x, mp, out);
}

// Round 5
// 209.577 us; speedup vs baseline: 1.8184x; 1.8184x over previous
//
#include <hip/hip_runtime.h>
#include <hip/hip_bf16.h>

#define NCOL 10752   // 512*21
#define NG 15
#define NTILES 23

typedef __bf16 bf16;
typedef __attribute__((ext_vector_type(8))) __bf16 bf16x8;
typedef __attribute__((ext_vector_type(4))) float f32x4;

__constant__ int c_gsize[NG]  = {64,128,256,96,160,224,192,288,320,112,80,48,32,16,32};
__constant__ int c_gstart[NG] = {0,64,192,448,544,704,928,1120,1408,1728,1840,1920,1968,2000,2016};
// tiles sorted by descending group size; grid.x = colb (adjacent blocks stream
// adjacent 512B col-segments of the same X k-rows -> page coalescing + L3 reuse)
__constant__ int c_tgrp[NTILES] = {8,8,8,7,7,7,2,2,5,5,6,6,4,4,1,9,3,10,0,11,12,14,13};
__constant__ int c_trow[NTILES] = {0,128,256,0,128,256,0,128,0,128,0,128,0,128,0,0,0,0,0,0,0,0,0};

struct MatPtrs { const float* p[NG]; };

constexpr int BN = 128, BK = 32, BKp = 40;

// Barrier-free K-loop: each wave owns a private X^T LDS quarter (its 64 cols)
// and loads its A fragments directly from global (M is L2-resident, 1.7MB).
// No __syncthreads in the loop -> no convoy, every wave keeps its next
// iteration's loads in flight continuously.
__global__ __launch_bounds__(256)
void matapply_kernel(const float* __restrict__ x, MatPtrs mats, float* __restrict__ out)
{
    __shared__ bf16 sB[4][64][BKp];   // [wave][local col][k], k-chunk XOR-swizzled

    const int tid    = threadIdx.x;
    const int colb   = blockIdx.x * BN;
    const int tileid = blockIdx.y;

    const int grp  = c_tgrp[tileid];
    const int row0 = c_trow[tileid];
    const int g    = c_gsize[grp];
    const int s    = c_gstart[grp];
    const float* __restrict__ M = mats.p[grp];

    const int wave = tid >> 6;
    const int lane = tid & 63;
    const int wr   = (wave & 1) * 64;        // wave's row half
    const int wc   = (wave >> 1) * 64;       // wave's col half
    const int lm   = lane & 15;
    const int kq   = lane >> 4;              // k-quad: frag layout AND staging k-group
    const int kb   = kq * 8;

    bf16 (* __restrict__ sBw)[BKp] = sB[wave];

    const int nIter = (g + BK - 1) / BK;

    f32x4 acc[4][4];
    #pragma unroll
    for (int i = 0; i < 4; i++)
        #pragma unroll
        for (int j = 0; j < 4; j++)
            acc[i][j] = (f32x4){0.f, 0.f, 0.f, 0.f};

    // A addressing: frag i -> row row0+wr+i*16+lm, k = k0+kb..+7 (2x float4)
    int arow[4]; bool arok[4];
    #pragma unroll
    for (int i = 0; i < 4; i++) {
        arow[i] = row0 + wr + i * 16 + lm;
        arok[i] = arow[i] < g;
    }

    // X staging: lane loads k-rows (k0+kb+q), q=0..7, cols colb+wc+lm*4..+3
    const float* xbase = x + (size_t)(s + kb) * NCOL + colb + wc + lm * 4;

    float4 a4[4][2];   // A prefetch (depth 1)
    float4 xv[8];      // X prefetch (depth 1)

    auto issueA = [&](int k0) {
        #pragma unroll
        for (int i = 0; i < 4; i++) {
            a4[i][0] = make_float4(0.f, 0.f, 0.f, 0.f);
            a4[i][1] = make_float4(0.f, 0.f, 0.f, 0.f);
            if (arok[i] && (k0 + kb) < g) {      // g mult of 16, kb mult of 8 -> full 8-chunk valid
                const float* p = M + (size_t)arow[i] * g + k0 + kb;
                a4[i][0] = *(const float4*)p;
                a4[i][1] = *(const float4*)(p + 4);
            }
        }
    };
    auto issueX = [&](int k0) {
        const float* p = xbase + (size_t)k0 * NCOL;
        #pragma unroll
        for (int q = 0; q < 8; q++)
            xv[q] = *(const float4*)(p + (size_t)q * NCOL);
        // rows beyond g read the next group's data; A k-chunks >= g are zeroed
        // so they contribute 0. Always in-bounds of x (checked per group table).
    };

    issueA(0);
    issueX(0);

    for (int it = 0; it < nIter; ++it) {
        const int k0n = (it + 1) * BK;

        // ---- A: convert current (waits only A's vmcnt), then re-issue ----
        bf16x8 af[4];
        #pragma unroll
        for (int i = 0; i < 4; i++) {
            #pragma unroll
            for (int e = 0; e < 4; e++) {
                af[i][e]     = (bf16)(((const float*)&a4[i][0])[e]);
                af[i][4 + e] = (bf16)(((const float*)&a4[i][1])[e]);
            }
        }
        if (k0n < g) issueA(k0n);

        // ---- X: transpose-convert into private quarter, then re-issue ----
        #pragma unroll
        for (int cc = 0; cc < 4; cc++) {
            const int lc = lm * 4 + cc;          // local col 0..63
            bf16x8 w;
            #pragma unroll
            for (int q = 0; q < 8; q++)
                w[q] = (bf16)(((const float*)&xv[q])[cc]);
            *(bf16x8*)&sBw[lc][kb ^ (((lc >> 3) & 3) << 3)] = w;
        }
        if (k0n < g) issueX(k0n);

        // ---- B frags (same-wave lgkmcnt ordering, no barrier) + MFMA ----
        bf16x8 bfr[4];
        #pragma unroll
        for (int j = 0; j < 4; j++) {
            const int lc = j * 16 + lm;
            bfr[j] = *(const bf16x8*)&sBw[lc][kb ^ (((lc >> 3) & 3) << 3)];
        }
        #pragma unroll
        for (int i = 0; i < 4; i++)
            #pragma unroll
            for (int j = 0; j < 4; j++)
                acc[i][j] = __builtin_amdgcn_mfma_f32_16x16x32_bf16(af[i], bfr[j], acc[i][j], 0, 0, 0);
    }

    // ---- epilogue: C/D layout col=lane&15, row=(lane>>4)*4+reg ----
    #pragma unroll
    for (int i = 0; i < 4; i++) {
        #pragma unroll
        for (int r = 0; r < 4; r++) {
            int row = row0 + wr + i * 16 + kq * 4 + r;
            if (row < g) {
                float* orow = out + (size_t)(s + row) * NCOL + colb + wc;
                #pragma unroll
                for (int j = 0; j < 4; j++)
                    orow[j * 16 + lm] = acc[i][j][r];
            }
        }
    }
}

extern "C" void kernel_launch(void* const* d_in, const int* in_sizes, int n_in,
                              void* d_out, int out_size, void* d_ws, size_t ws_size,
                              hipStream_t stream)
{
    const float* x = (const float*)d_in[0];
    MatPtrs mp;
    for (int i = 0; i < NG; i++) mp.p[i] = (const float*)d_in[1 + i];
    float* out = (float*)d_out;

    dim3 grid(NCOL / BN, NTILES);   // (84, 23): colb fastest
    dim3 block(256);
    matapply_kernel<<<grid, block, 0, stream>>>(x, mp, out);
}